// Round 10
// baseline (289.309 us; speedup 1.0000x reference)
//
#include <hip/hip_runtime.h>
#include <hip/hip_bf16.h>

// SelfAttention: x(4,2048,1024) fp32 -> QKV proj -> 8-head attn (hd=128) -> out proj.
// fp32 in/out; fp16 MFMA internally (absmax 9.77e-4, 2x margin under threshold).
// R21: attention v14 = split-K flash. v10's ledger: DS pipe ~92us is the attn
// floor (17 b128 reads per 17 MFMAs); v11 proved 2-frag reuse halves DS but
// regressed at 2 waves/SIMD (sum-of-pipes). v14 synthesis: same 1024-block x
// 4-wave grid as v10, but each wave owns 32 q-rows x HALF the keys (waves 0,1:
// keys [0,1024); waves 2,3: [1024,2048)). Every K/V read feeds 2 MFMAs; total
// DS reads halve; 43KB LDS single-buffered both pairs -> 3 indep blocks/CU
// (12 waves, overlap regime). Clampless softmax => partials add exactly:
// epilogue waves 2,3 dump acc+l to LDS (stride 73, conflict-free), waves 0,1
// add + store. Staging = v10's (verified), COMPUTE = v11's (verified).
// R20 banked: fused V-transpose in QKV epilogue, 275.6us total, attn 103.4.
//
// Workspace ladder:
//   ws >= 72 MiB : full path (prep; QKV GEMM w/ fused V-transpose; flash14;
//                  out GEMM). 4 launches.
//   ws >= 64 MiB : half-split variant (2 halves of x / batch pairs).
//   ws >= 24 MiB : per-batch loop of the same kernels.
//   else         : per-batch gemm64 path (16 MiB), weights read fp32 directly.

typedef __attribute__((ext_vector_type(8))) short short8;
typedef __attribute__((ext_vector_type(4))) short short4v;
typedef __attribute__((ext_vector_type(4))) float floatx4;
typedef __attribute__((ext_vector_type(8))) _Float16 half8;

#define MFMA_F16(a, b, c) __builtin_amdgcn_mfma_f32_16x16x32_f16( \
    __builtin_bit_cast(half8, (a)), __builtin_bit_cast(half8, (b)), (c), 0, 0, 0)

static constexpr int BATCH  = 4;
static constexpr int NHEADS = 8;
static constexpr int SEQ    = 2048;
static constexpr int HD     = 128;
static constexpr int DMODEL = 1024;
static constexpr int MROWS  = BATCH * SEQ;   // 8192
static constexpr int NQKV   = 3 * DMODEL;    // 3072

// (1/sqrt(128)) * log2(e): folded into Q at QKV-GEMM epilogue
#define QSCALE2 0.12752283786512624f

static __device__ __forceinline__ short f16bits(float v) {
    return __builtin_bit_cast(short, (_Float16)v);
}

template <typename T>
static __device__ __forceinline__ short8 load8_f16(const T* p) {
    if constexpr (sizeof(T) == 2) {
        return *(const short8*)p;
    } else {
        const float4 f0 = *(const float4*)p;
        const float4 f1 = *(const float4*)(p + 4);
        short8 r;
        r[0] = f16bits(f0.x); r[1] = f16bits(f0.y);
        r[2] = f16bits(f0.z); r[3] = f16bits(f0.w);
        r[4] = f16bits(f1.x); r[5] = f16bits(f1.y);
        r[6] = f16bits(f1.z); r[7] = f16bits(f1.w);
        return r;
    }
}

static __device__ __forceinline__ void storeC(float* C, size_t idx, float v) {
    C[idx] = v;
}
static __device__ __forceinline__ void storeC(_Float16* C, size_t idx, float v) {
    C[idx] = (_Float16)v;
}

// async global -> LDS, 16B/lane. LDS dest: per-lane ptr == wave base + lane*16.
static __device__ __forceinline__ void gload16(const short* g, short* l) {
    __builtin_amdgcn_global_load_lds(
        (const __attribute__((address_space(1))) void*)g,
        (__attribute__((address_space(3))) void*)l, 16, 0, 0);
}

// ---------------------------------------------------------------------------
// prep: weight transposes (+ optional fused x conversion).
// z = 0..3 : W[z] (K x N fp32) -> Wt + z*K*N ([N][K] fp16), 32x32 tile (x,y)
// z = 4..7 : convert x fp32 -> fp16, chunk = (z-4)*1024 + y*32 + x
// Launch with gridDim.z = 4 for weights-only (x may be nullptr).
// ---------------------------------------------------------------------------
__global__ __launch_bounds__(256)
void prep(const float* __restrict__ x, short* __restrict__ xb,
          const float* __restrict__ W0, const float* __restrict__ W1,
          const float* __restrict__ W2, const float* __restrict__ W3,
          short* __restrict__ Wt, int K, int N)
{
    __shared__ short T[32][33];
    const int z = blockIdx.z;
    if (z >= 4) {
        const size_t chunk = ((size_t)(z - 4) * 1024 + blockIdx.y * 32 + blockIdx.x);
        const size_t i = (chunk * 256 + threadIdx.x) * 8;
        *(short8*)&xb[i] = load8_f16(&x[i]);
        return;
    }
    const float* W = (z == 0) ? W0 : (z == 1) ? W1 : (z == 2) ? W2 : W3;
    short* Wtz = Wt + (size_t)z * K * N;

    const int n0 = blockIdx.x * 32, k0 = blockIdx.y * 32;
    const int r = threadIdx.x >> 3, c4 = (threadIdx.x & 7) * 4;

    const float4 v = *(const float4*)&W[(size_t)(k0 + r) * N + n0 + c4];
    T[r][c4 + 0] = f16bits(v.x);
    T[r][c4 + 1] = f16bits(v.y);
    T[r][c4 + 2] = f16bits(v.z);
    T[r][c4 + 3] = f16bits(v.w);
    __syncthreads();

    short4v o;
    o[0] = T[c4 + 0][r]; o[1] = T[c4 + 1][r];
    o[2] = T[c4 + 2][r]; o[3] = T[c4 + 3][r];
    *(short4v*)&Wtz[(size_t)(n0 + r) * K + k0 + c4] = o;
}

// standalone x fp32 -> fp16 chunk converter (per-batch / per-half paths)
__global__ __launch_bounds__(256)
void convx(const float* __restrict__ x, short* __restrict__ xb)
{
    const size_t i = ((size_t)blockIdx.x * 256 + threadIdx.x) * 8;
    *(short8*)&xb[i] = load8_f16(&x[i]);
}

// ---------------------------------------------------------------------------
// 128x128-tile GEMM, BK=64, global_load_lds(16B), XOR chunk-slot swizzle.
// QKV=true: N=3072; writes Q,K [b][h][s][d] and V TRANSPOSED [b][h][d][s]
//           (fused transpose_v: 4 consecutive s pack into one 8B store) at
//           slab spacing qkvStride elems; Q pre-scaled by QSCALE2.
// ---------------------------------------------------------------------------
template <typename OutT, bool QKV>
__global__ __launch_bounds__(256)
void gemm128(const short* __restrict__ A, const short* __restrict__ Bt,
             OutT* __restrict__ C, int M, int N, int K, size_t qkvStride)
{
    __shared__ __align__(16) short As[128 * 64];   // 16 KB
    __shared__ __align__(16) short Bs[128 * 64];   // 16 KB

    const int tid  = threadIdx.x;
    const int lane = tid & 63;
    const int w    = tid >> 6;
    const int quad = lane >> 4;
    const int l16  = lane & 15;

    const int m0 = blockIdx.x * 128;
    const int n0 = blockIdx.y * 128;
    const int wm = (w >> 1) * 64;
    const int wn = (w & 1) * 64;

    floatx4 acc[4][4] = {};

    const int srow   = tid >> 3;                     // 0..31
    const int schunk = (tid & 7) ^ (srow & 7);
    const short* aG = A  + (size_t)(m0 + srow) * K + schunk * 8;
    const short* bG = Bt + (size_t)(n0 + srow) * K + schunk * 8;
    short* aL = As + tid * 8;                        // round r at +r*2048
    short* bL = Bs + tid * 8;

    const int fsw = l16 & 7;                         // frag-read swizzle term

    for (int k0 = 0; k0 < K; k0 += 64) {
        __syncthreads();                             // WAR
        #pragma unroll
        for (int r = 0; r < 4; ++r) {                // row&7 invariant mod 32
            gload16(aG + k0 + (size_t)(r * 32) * K, aL + r * 2048);
            gload16(bG + k0 + (size_t)(r * 32) * K, bL + r * 2048);
        }
        __syncthreads();                             // RAW (vmcnt drained)

        #pragma unroll
        for (int kk = 0; kk < 2; ++kk) {
            short8 af[4], bf[4];
            #pragma unroll
            for (int mi = 0; mi < 4; ++mi)
                af[mi] = *(short8*)&As[(wm + mi * 16 + l16) * 64 +
                                       (((kk * 4 + quad) ^ fsw) * 8)];
            #pragma unroll
            for (int ni = 0; ni < 4; ++ni)
                bf[ni] = *(short8*)&Bs[(wn + ni * 16 + l16) * 64 +
                                       (((kk * 4 + quad) ^ fsw) * 8)];

            #pragma unroll
            for (int mi = 0; mi < 4; ++mi)
                #pragma unroll
                for (int ni = 0; ni < 4; ++ni)
                    acc[mi][ni] = MFMA_F16(af[mi], bf[ni], acc[mi][ni]);
        }
    }

    #pragma unroll
    for (int mi = 0; mi < 4; ++mi)
        #pragma unroll
        for (int ni = 0; ni < 4; ++ni) {
            if constexpr (QKV) {
                const int n   = n0 + wn + ni * 16 + l16;
                const int qkv = n >> 10, rem = n & 1023;
                const int hh  = rem >> 7, d = rem & 127;
                const int mb  = m0 + wm + mi * 16 + quad * 4;   // 4 consec rows
                const int bb  = mb >> 11, s = mb & 2047;        // s % 4 == 0
                if (qkv == 2) {
                    // V transposed [b][h][d][s]: one aligned 8B store of 4 s
                    short4v pk;
                    #pragma unroll
                    for (int r = 0; r < 4; ++r)
                        pk[r] = f16bits(acc[mi][ni][r]);
                    *(short4v*)&((short*)C)[2 * qkvStride +
                        (((size_t)bb * NHEADS + hh) * HD + d) * SEQ + s] = pk;
                } else {
                    const float sc = (qkv == 0) ? QSCALE2 : 1.0f;
                    #pragma unroll
                    for (int r = 0; r < 4; ++r)
                        storeC(C, (size_t)qkv * qkvStride +
                                  (((size_t)bb * NHEADS + hh) * SEQ + s + r) * HD + d,
                               acc[mi][ni][r] * sc);
                }
            } else {
                #pragma unroll
                for (int r = 0; r < 4; ++r) {
                    const int m = m0 + wm + mi * 16 + quad * 4 + r;
                    const int n = n0 + wn + ni * 16 + l16;
                    storeC(C, (size_t)m * N + n, acc[mi][ni][r]);
                }
            }
        }
}

// ---------------------------------------------------------------------------
// Attention v14: split-K flash. 4 waves / 64 q-rows / block; wave w:
// qhalf = w&1 (rows q0+qhalf*32..+31, two 16-row frags), khalf = w>>1
// (keys khalf*1024..+1023). Every K/V frag read feeds 2 MFMAs. K/V for both
// pairs single-buffered (43KB LDS, 3 blocks/CU); 2 barriers/iter; 32 iters.
// Clampless exp2 softmax (Q pre-scaled), l-sum via ones-MFMA, setprio around
// MFMA clusters. Epilogue: khalf=1 waves dump acc+l to LDS (stride 73 floats,
// conflict-free); khalf=0 waves add partials and store O.
// ---------------------------------------------------------------------------
__global__ __launch_bounds__(256)
void attn_flash14(const short* __restrict__ Q, const short* __restrict__ K,
                  const short* __restrict__ Vt, _Float16* __restrict__ O)
{
    __shared__ __align__(16) short POOL[21504];       // 43008 B
    // layout: Ks pair p @ p*4096 (32x128); Vs pair p @ 8192+p*4096 (128x32);
    //         P wave w @ 16384 + w*1280 (32 rows x 40)

    const int tid  = threadIdx.x;
    const int lane = tid & 63;
    const int w    = tid >> 6;            // 0..3
    const int quad = lane >> 4;
    const int l16  = lane & 15;
    const int qhalf = w & 1;              // q-row half
    const int khalf = w >> 1;             // key half

    const int h  = blockIdx.x & 7;        // blockIdx%8 = head -> XCD L2 locality
    const int qi = blockIdx.x >> 3;       // 0..31
    const int b  = blockIdx.y;
    const int q0 = qi * 64;

    const short* Qh  = Q  + (((size_t)b * NHEADS + h) * SEQ) * HD;
    const short* Kh  = K  + (((size_t)b * NHEADS + h) * SEQ) * HD;
    const short* Vth = Vt + (((size_t)b * NHEADS + h) * HD) * SEQ;  // [d][s]

    // Q fragments (pre-scaled): 2 m-frags, rows q0 + qhalf*32 + mi*16 + l16
    short8 qf[2][4];
    #pragma unroll
    for (int mi = 0; mi < 2; ++mi) {
        const int qrow = q0 + qhalf * 32 + mi * 16 + l16;
        #pragma unroll
        for (int c = 0; c < 4; ++c)
            qf[mi][c] = *(const short8*)&Qh[(size_t)qrow * HD + c * 32 + quad * 8];
    }

    // staging addresses (v10-verified): per 32x128 K tile, 512 slots
    // {tid, tid+256}: slot s: row=s>>4, chunk=(s&15)^(row&15).
    // per 128x32 V tile: slot s: row=s>>2, chunk=(s&3)^((row>>1)&3).
    const int kr0 = tid >> 4, kc0 = tid & 15;
    const int kr1 = kr0 + 16;
    const short* kGa = Kh + (size_t)kr0 * HD + ((kc0 ^ (kr0 & 15)) * 8);
    const short* kGb = Kh + (size_t)kr1 * HD + ((kc0 ^ (kr1 & 15)) * 8);
    const int vr0 = tid >> 2, vp0 = tid & 3;
    const short* vGa = Vth + (size_t)vr0 * SEQ + ((vp0 ^ ((vr0 >> 1) & 3)) * 8);
    const short* vGb = Vth + (size_t)(vr0 + 64) * SEQ + ((vp0 ^ ((vr0 >> 1) & 3)) * 8);

    floatx4 acc[2][8] = {};
    floatx4 acc9[2] = {};                 // l-sum accumulators (P @ ones)

    short8 ones;
    #pragma unroll
    for (int j = 0; j < 8; ++j) ones[j] = 0x3C00;   // fp16 1.0

    const int fswV = (l16 >> 1) & 3;      // Vs frag swizzle
    short* Pw = POOL + 16384 + w * 1280;
    const short* Kb = POOL + khalf * 4096;
    const short* Vb = POOL + 8192 + khalf * 4096;

    for (int t = 0; t < SEQ / 64; ++t) {  // 32 iterations; pair p tile g=p*32+t
        __syncthreads();                  // WAR: all waves done with prev tiles
        #pragma unroll
        for (int p = 0; p < 2; ++p) {
            const int g = p * 32 + t;
            const size_t ko = (size_t)g * 32 * HD;
            const size_t vo = (size_t)g * 32;
            short* kDst = POOL + p * 4096;
            short* vDst = POOL + 8192 + p * 4096;
            gload16(kGa + ko, kDst + tid * 8);
            gload16(kGb + ko, kDst + (tid + 256) * 8);
            gload16(vGa + vo, vDst + tid * 8);
            gload16(vGb + vo, vDst + (tid + 256) * 8);
        }
        __syncthreads();                  // RAW: DMA drained at barrier

        // S = Q K^T: 32q x 32keys per wave, K frags reused across m-frags
        floatx4 s[2][2] = {};
        __builtin_amdgcn_s_setprio(1);
        #pragma unroll
        for (int c = 0; c < 4; ++c) {
            const int k_ = c * 4 + quad;
            short8 kf0 = *(short8*)&Kb[l16 * 128 + ((k_ ^ l16) * 8)];
            short8 kf1 = *(short8*)&Kb[(16 + l16) * 128 + ((k_ ^ l16) * 8)];
            #pragma unroll
            for (int mi = 0; mi < 2; ++mi) {
                s[mi][0] = MFMA_F16(qf[mi][c], kf0, s[mi][0]);
                s[mi][1] = MFMA_F16(qf[mi][c], kf1, s[mi][1]);
            }
        }
        __builtin_amdgcn_s_setprio(0);

        // softmax (Q pre-scaled, clampless): p = 2^s -> wave-private LDS
        #pragma unroll
        for (int mi = 0; mi < 2; ++mi)
            #pragma unroll
            for (int r = 0; r < 4; ++r) {
                const float p0 = __builtin_amdgcn_exp2f(s[mi][0][r]);
                const float p1 = __builtin_amdgcn_exp2f(s[mi][1][r]);
                const int prow = mi * 16 + quad * 4 + r;
                Pw[prow * 40 + l16]      = f16bits(p0);
                Pw[prow * 40 + 16 + l16] = f16bits(p1);
            }
        short8 pf[2];
        #pragma unroll
        for (int mi = 0; mi < 2; ++mi)
            pf[mi] = *(short8*)&Pw[(mi * 16 + l16) * 40 + quad * 8];

        // O += P @ V (+ l-sum on MFMA pipe); V frags reused across m-frags
        __builtin_amdgcn_s_setprio(1);
        #pragma unroll
        for (int mi = 0; mi < 2; ++mi)
            acc9[mi] = MFMA_F16(pf[mi], ones, acc9[mi]);
        #pragma unroll
        for (int hc = 0; hc < 8; ++hc) {
            short8 vf = *(short8*)&Vb[(hc * 16 + l16) * 32 + ((quad ^ fswV) * 8)];
            #pragma unroll
            for (int mi = 0; mi < 2; ++mi)
                acc[mi][hc] = MFMA_F16(pf[mi], vf, acc[mi][hc]);
        }
        __builtin_amdgcn_s_setprio(0);
    }

    // combine split-K partials: khalf=1 dumps, khalf=0 adds + stores.
    __syncthreads();
    float* SP = (float*)POOL;             // 43008 B >= 128 lanes * 73 * 4B
    if (khalf == 1) {
        float* dst = SP + (size_t)(qhalf * 64 + lane) * 73;
        #pragma unroll
        for (int mi = 0; mi < 2; ++mi) {
            #pragma unroll
            for (int hc = 0; hc < 8; ++hc)
                #pragma unroll
                for (int r = 0; r < 4; ++r)
                    dst[mi * 32 + hc * 4 + r] = acc[mi][hc][r];
            #pragma unroll
            for (int r = 0; r < 4; ++r)
                dst[64 + mi * 4 + r] = acc9[mi][r];
        }
    }
    __syncthreads();
    if (khalf == 0) {
        const float* src = SP + (size_t)(qhalf * 64 + lane) * 73;
        #pragma unroll
        for (int mi = 0; mi < 2; ++mi) {
            #pragma unroll
            for (int hc = 0; hc < 8; ++hc)
                #pragma unroll
                for (int r = 0; r < 4; ++r)
                    acc[mi][hc][r] += src[mi * 32 + hc * 4 + r];
            #pragma unroll
            for (int r = 0; r < 4; ++r)
                acc9[mi][r] += src[64 + mi * 4 + r];
        }
        #pragma unroll
        for (int mi = 0; mi < 2; ++mi) {
            float rinv[4];
            #pragma unroll
            for (int r = 0; r < 4; ++r)
                rinv[r] = 1.0f / fmaxf(acc9[mi][r], 1e-30f);
            #pragma unroll
            for (int hc = 0; hc < 8; ++hc)
                #pragma unroll
                for (int r = 0; r < 4; ++r) {
                    const int row = q0 + qhalf * 32 + mi * 16 + quad * 4 + r;
                    O[((size_t)b * SEQ + row) * DMODEL + h * HD + hc * 16 + l16] =
                        (_Float16)(acc[mi][hc][r] * rinv[r]);
                }
        }
    }
}

// ---------------------------------------------------------------------------
// Minimal-workspace kernels (per-batch gemm64 path)
// ---------------------------------------------------------------------------
template <typename AT, typename OutT>
__global__ __launch_bounds__(256)
void gemm64(const AT* __restrict__ A, const float* __restrict__ W,
            OutT* __restrict__ C, int M, int N, int K, int headsplit)
{
    __shared__ __align__(16) short As[64][32];
    __shared__ __align__(16) short Bs[64][32];

    const int tid  = threadIdx.x;
    const int lane = tid & 63;
    const int w    = tid >> 6;
    const int quad = lane >> 4;
    const int l16  = lane & 15;

    const int m0 = blockIdx.x * 64;
    const int n0 = blockIdx.y * 64;
    const int wm = (w >> 1) * 32;
    const int wn = (w & 1) * 32;

    floatx4 acc[2][2] = {};

    const int arow = tid >> 2, acol = (tid & 3) * 8;
    const int brow = tid >> 3, bcol = (tid & 7) * 8;

    const AT*    aptr = A + (size_t)(m0 + arow) * K + acol;
    const float* bptr = W + (size_t)brow * N + n0 + bcol;

    for (int k0 = 0; k0 < K; k0 += 32) {
        short8 av = load8_f16(aptr + k0);
        short8 bv = load8_f16(bptr + (size_t)k0 * N);
        __syncthreads();
        *(short8*)&As[arow][acol] = av;
        #pragma unroll
        for (int j = 0; j < 8; ++j)
            Bs[bcol + j][brow] = bv[j];
        __syncthreads();

        short8 af0 = *(short8*)&As[wm + l16][quad * 8];
        short8 af1 = *(short8*)&As[wm + 16 + l16][quad * 8];
        short8 bf0 = *(short8*)&Bs[wn + l16][quad * 8];
        short8 bf1 = *(short8*)&Bs[wn + 16 + l16][quad * 8];

        acc[0][0] = MFMA_F16(af0, bf0, acc[0][0]);
        acc[0][1] = MFMA_F16(af0, bf1, acc[0][1]);
        acc[1][0] = MFMA_F16(af1, bf0, acc[1][0]);
        acc[1][1] = MFMA_F16(af1, bf1, acc[1][1]);
    }

    #pragma unroll
    for (int mi = 0; mi < 2; ++mi)
        #pragma unroll
        for (int ni = 0; ni < 2; ++ni)
            #pragma unroll
            for (int r = 0; r < 4; ++r) {
                const int m = m0 + wm + mi * 16 + quad * 4 + r;
                const int n = n0 + wn + ni * 16 + l16;
                const float v = acc[mi][ni][r];
                if (headsplit) {
                    const int b = m >> 11, nn = m & 2047;
                    const int h = n >> 7,  d  = n & 127;
                    storeC(C, (((size_t)b * NHEADS + h) * SEQ + nn) * HD + d, v);
                } else {
                    storeC(C, (size_t)m * N + n, v);
                }
            }
}

__global__ __launch_bounds__(256)
void attn_flash(const short* __restrict__ Q, const short* __restrict__ K,
                const short* __restrict__ V, _Float16* __restrict__ O)
{
    __shared__ __align__(16) short Ksf[32][136];
    __shared__ __align__(16) short Vtl[HD][40];
    __shared__ __align__(16) short Pldsf[4][16][40];

    const int tid  = threadIdx.x;
    const int lane = tid & 63;
    const int w    = tid >> 6;
    const int quad = lane >> 4;
    const int l16  = lane & 15;

    const int q0 = blockIdx.x * 64;
    const int h  = blockIdx.y;
    const int b  = blockIdx.z;

    const size_t headoff = ((size_t)b * NHEADS + h) * SEQ * HD;
    const short* Qh = Q + headoff;
    const short* Kh = K + headoff;
    const short* Vh = V + headoff;

    const float scale = 0.08838834764831845f;

    const int qrow = q0 + w * 16 + l16;
    short8 qf[4];
    #pragma unroll
    for (int c = 0; c < 4; ++c)
        qf[c] = *(const short8*)&Qh[(size_t)qrow * HD + c * 32 + quad * 8];

    float mrow[4], lrow[4];
    #pragma unroll
    for (int r = 0; r < 4; ++r) { mrow[r] = -1e30f; lrow[r] = 0.f; }
    floatx4 acc[8] = {};

    const int krow = tid >> 4, kcol = (tid & 15) * 8;
    const int vkey = tid & 31;
    const int vhd  = (tid >> 5) * 16;

    for (int kt = 0; kt < SEQ; kt += 32) {
        const short* Kt = Kh + (size_t)kt * HD;
        short8 k0v = *(const short8*)(Kt + (size_t)tid * 8);
        short8 k1v = *(const short8*)(Kt + (size_t)(tid + 256) * 8);
        short8 v0 = *(const short8*)&Vh[(size_t)(kt + vkey) * HD + vhd];
        short8 v1 = *(const short8*)&Vh[(size_t)(kt + vkey) * HD + vhd + 8];

        __syncthreads();
        *(short8*)&Ksf[krow][kcol]      = k0v;
        *(short8*)&Ksf[krow + 16][kcol] = k1v;
        #pragma unroll
        for (int j = 0; j < 8; ++j) {
            Vtl[vhd + j][vkey]     = v0[j];
            Vtl[vhd + 8 + j][vkey] = v1[j];
        }
        __syncthreads();

        floatx4 s0 = {}, s1 = {};
        #pragma unroll
        for (int c = 0; c < 4; ++c) {
            short8 kf0 = *(short8*)&Ksf[l16][c * 32 + quad * 8];
            short8 kf1 = *(short8*)&Ksf[16 + l16][c * 32 + quad * 8];
            s0 = MFMA_F16(qf[c], kf0, s0);
            s1 = MFMA_F16(qf[c], kf1, s1);
        }

        float p0[4], p1[4], alpha[4];
        #pragma unroll
        for (int r = 0; r < 4; ++r) {
            const float a  = s0[r] * scale;
            const float bb = s1[r] * scale;
            float mx = fmaxf(a, bb);
            mx = fmaxf(mx, __shfl_xor(mx, 1));
            mx = fmaxf(mx, __shfl_xor(mx, 2));
            mx = fmaxf(mx, __shfl_xor(mx, 4));
            mx = fmaxf(mx, __shfl_xor(mx, 8));
            const float mnew = fmaxf(mrow[r], mx);
            alpha[r] = __expf(mrow[r] - mnew);
            mrow[r]  = mnew;
            p0[r] = __expf(a - mnew);
            p1[r] = __expf(bb - mnew);
            float rs = p0[r] + p1[r];
            rs += __shfl_xor(rs, 1);
            rs += __shfl_xor(rs, 2);
            rs += __shfl_xor(rs, 4);
            rs += __shfl_xor(rs, 8);
            lrow[r] = lrow[r] * alpha[r] + rs;
        }
        #pragma unroll
        for (int hc = 0; hc < 8; ++hc)
            #pragma unroll
            for (int r = 0; r < 4; ++r)
                acc[hc][r] *= alpha[r];

        #pragma unroll
        for (int r = 0; r < 4; ++r) {
            Pldsf[w][quad * 4 + r][l16]      = f16bits(p0[r]);
            Pldsf[w][quad * 4 + r][16 + l16] = f16bits(p1[r]);
        }
        __syncthreads();

        short8 pf = *(short8*)&Pldsf[w][l16][quad * 8];
        #pragma unroll
        for (int hc = 0; hc < 8; ++hc) {
            short8 vf = *(short8*)&Vtl[hc * 16 + l16][quad * 8];
            acc[hc] = MFMA_F16(pf, vf, acc[hc]);
        }
    }

    #pragma unroll
    for (int hc = 0; hc < 8; ++hc)
        #pragma unroll
        for (int r = 0; r < 4; ++r) {
            const int row = q0 + w * 16 + quad * 4 + r;
            const float val = acc[hc][r] / fmaxf(lrow[r], 1e-30f);
            O[((size_t)b * SEQ + row) * DMODEL + h * HD + hc * 16 + l16] =
                (_Float16)val;
        }
}

extern "C" void kernel_launch(void* const* d_in, const int* in_sizes, int n_in,
                              void* d_out, int out_size, void* d_ws, size_t ws_size,
                              hipStream_t stream)
{
    const float* x  = (const float*)d_in[0];
    const float* Wq = (const float*)d_in[1];
    const float* Wk = (const float*)d_in[2];
    const float* Wv = (const float*)d_in[3];
    const float* Wo = (const float*)d_in[4];
    float* out = (float*)d_out;

    const size_t bufElems = (size_t)MROWS * DMODEL;   // 8 Mi elems (16 MiB fp16)
    const size_t batElems = (size_t)SEQ * DMODEL;     // 2 Mi elems (4 MiB fp16)
    const size_t MiB = 1024 * 1024;
    dim3 tt(256);

    if (ws_size >= 72 * MiB) {
        // layout (MiB): [0,16) xb -> later Ab | [16,32) Qb | [32,48) Kb |
        // [48,64) Vt (written transposed by QKV GEMM) | [64,72) Wt
        short* xb    = (short*)d_ws;
        short* Qb    = xb + bufElems;
        short* Kb    = xb + 2 * bufElems;
        short* Vtb   = xb + 3 * bufElems;      // V transposed [b][h][d][s]
        short* Wtall = xb + 4 * bufElems;      // Wq^T,Wk^T,Wv^T,Wo^T contiguous
        short* Wto   = Wtall + 3 * (size_t)DMODEL * DMODEL;
        short* Ab    = xb;                     // alias: xb dead after QKV GEMM

        prep<<<dim3(32, 32, 8), tt, 0, stream>>>(
            x, xb, Wq, Wk, Wv, Wo, Wtall, DMODEL, DMODEL);

        gemm128<_Float16, true><<<dim3(MROWS / 128, NQKV / 128), tt, 0, stream>>>(
            xb, Wtall, (_Float16*)Qb, MROWS, NQKV, DMODEL, bufElems);

        attn_flash14<<<dim3(NHEADS * (SEQ / 64), BATCH), tt, 0, stream>>>(
            Qb, Kb, Vtb, (_Float16*)Ab);

        gemm128<float, false><<<dim3(MROWS / 128, DMODEL / 128), tt, 0, stream>>>(
            Ab, Wto, out, MROWS, DMODEL, DMODEL, 0);
    } else if (ws_size >= 64 * MiB) {
        // half-split: [0,8) xb (half of x) -> later Ab (per half) | [8,24) Qb |
        // [24,40) Kb | [40,56) Vt (transposed by GEMM) | [56,64) Wt
        short* xb    = (short*)d_ws;                  // 4 Mi elems
        short* Qb    = xb + 2 * batElems;             // 8 Mi elems
        short* Kb    = Qb + 4 * batElems;
        short* Vtb   = Kb + 4 * batElems;
        short* Wtall = Vtb + 4 * batElems;
        short* Wto   = Wtall + 3 * (size_t)DMODEL * DMODEL;

        prep<<<dim3(32, 32, 4), tt, 0, stream>>>(     // weights only
            nullptr, nullptr, Wq, Wk, Wv, Wo, Wtall, DMODEL, DMODEL);

        for (int half = 0; half < 2; ++half) {
            const size_t off = (size_t)half * 2 * batElems;   // 2 batches
            convx<<<dim3(2048), tt, 0, stream>>>(x + off, xb);
            gemm128<_Float16, true><<<dim3(32, NQKV / 128), tt, 0, stream>>>(
                xb, Wtall, (_Float16*)(Qb + off), 2 * SEQ, NQKV, DMODEL,
                4 * batElems);                         // Q->K->Vt slab spacing
        }
        for (int half = 0; half < 2; ++half) {
            const size_t off = (size_t)half * 2 * batElems;
            attn_flash14<<<dim3(NHEADS * (SEQ / 64), 2), tt, 0, stream>>>(
                Qb + off, Kb + off, Vtb + off, (_Float16*)xb);   // Ab = xb
            gemm128<float, false><<<dim3(32, DMODEL / 128), tt, 0, stream>>>(
                xb, Wto, out + off, 2 * SEQ, DMODEL, DMODEL, 0);
        }
    } else if (ws_size >= 24 * MiB) {
        // per-batch: [0,4) xb -> Ab | [4,8) Qb | [8,12) Kb | [12,16) Vt |
        // [16,24) Wt.  4 launches per batch, sequential on stream.
        short* xb    = (short*)d_ws;
        short* Qb    = xb + batElems;
        short* Kb    = xb + 2 * batElems;
        short* Vtb   = xb + 3 * batElems;
        short* Wtall = xb + 4 * batElems;
        short* Wto   = Wtall + 3 * (size_t)DMODEL * DMODEL;

        prep<<<dim3(32, 32, 4), tt, 0, stream>>>(     // weights only
            nullptr, nullptr, Wq, Wk, Wv, Wo, Wtall, DMODEL, DMODEL);

        for (int b = 0; b < BATCH; ++b) {
            convx<<<dim3(1024), tt, 0, stream>>>(x + (size_t)b * batElems, xb);
            gemm128<_Float16, true><<<dim3(SEQ / 128, NQKV / 128), tt, 0, stream>>>(
                xb, Wtall, (_Float16*)Qb, SEQ, NQKV, DMODEL, batElems);
            attn_flash14<<<dim3(NHEADS * (SEQ / 64), 1), tt, 0, stream>>>(
                Qb, Kb, Vtb, (_Float16*)xb);          // Ab = xb
            gemm128<float, false><<<dim3(SEQ / 128, DMODEL / 128), tt, 0, stream>>>(
                xb, Wto, out + (size_t)b * batElems, SEQ, DMODEL, DMODEL, 0);
        }
    } else {
        // last resort (>=16 MiB): per-batch gemm64 path, weights read fp32.
        short* Qb = (short*)d_ws;
        short* Kb = Qb + batElems;
        short* Vb = Qb + 2 * batElems;
        short* Ab = Qb + 3 * batElems;

        dim3 gg(SEQ / 64, DMODEL / 64);
        for (int b = 0; b < BATCH; ++b) {
            const float* xb_ = x + (size_t)b * batElems;
            gemm64<float, _Float16><<<gg, tt, 0, stream>>>(
                xb_, Wq, (_Float16*)Qb, SEQ, DMODEL, DMODEL, 1);
            gemm64<float, _Float16><<<gg, tt, 0, stream>>>(
                xb_, Wk, (_Float16*)Kb, SEQ, DMODEL, DMODEL, 1);
            gemm64<float, _Float16><<<gg, tt, 0, stream>>>(
                xb_, Wv, (_Float16*)Vb, SEQ, DMODEL, DMODEL, 1);
            attn_flash<<<dim3(SEQ / 64, NHEADS, 1), tt, 0, stream>>>(
                Qb, Kb, Vb, (_Float16*)Ab);
            gemm64<short, float><<<gg, tt, 0, stream>>>(
                Ab, Wo, out + (size_t)b * batElems, SEQ, DMODEL, DMODEL, 0);
        }
    }
}

// Round 11
// 273.413 us; speedup vs baseline: 1.0581x; 1.0581x over previous
//
#include <hip/hip_runtime.h>
#include <hip/hip_bf16.h>

// SelfAttention: x(4,2048,1024) fp32 -> QKV proj -> 8-head attn (hd=128) -> out proj.
// fp32 in/out; fp16 MFMA internally (absmax 9.77e-4, 2x margin under threshold).
// R22: revert to R20-banked best config (275.6us) after v14 split-K regressed
// (117us attn: 43KB LDS + 112 VGPR -> 21% occupancy, lost inter-block overlap).
// FINAL LEDGER (attn variants, measured):
//   flash10+setprio (4w x 16q, 4 indep blocks/CU)  103.2us  <- BEST, this file
//   flash9  (8w lockstep)                          110.2
//   flash12 (cross-tile pipeline)                  110.2
//   flash14 (split-K, 2-frag reuse)                116.8
//   flash11 (2-wave, 2-frag reuse)                 129.0  (sum-of-pipes)
//   flash13 (swapped-QK graft)                     158.7  (8x bank conflicts)
// 103us ~= 1.13x the ~90us DS-pipe floor for this structure; further gains
// need the co-designed 32x32/8-phase rewrite (T2+T3+T4+T5 stack).
// Pipeline: prep (weights+x convert); QKV GEMM with fused V-transpose epilogue
// (R20, -6us vs separate transpose_v); flash10+prio; out GEMM. 4 launches.
//
// Workspace ladder:
//   ws >= 72 MiB : full path above.
//   ws >= 64 MiB : half-split variant (2 halves of x / batch pairs).
//   ws >= 24 MiB : per-batch loop of the same kernels.
//   else         : per-batch gemm64 path (16 MiB), weights read fp32 directly.

typedef __attribute__((ext_vector_type(8))) short short8;
typedef __attribute__((ext_vector_type(4))) short short4v;
typedef __attribute__((ext_vector_type(4))) float floatx4;
typedef __attribute__((ext_vector_type(8))) _Float16 half8;

#define MFMA_F16(a, b, c) __builtin_amdgcn_mfma_f32_16x16x32_f16( \
    __builtin_bit_cast(half8, (a)), __builtin_bit_cast(half8, (b)), (c), 0, 0, 0)

static constexpr int BATCH  = 4;
static constexpr int NHEADS = 8;
static constexpr int SEQ    = 2048;
static constexpr int HD     = 128;
static constexpr int DMODEL = 1024;
static constexpr int MROWS  = BATCH * SEQ;   // 8192
static constexpr int NQKV   = 3 * DMODEL;    // 3072

// (1/sqrt(128)) * log2(e): folded into Q at QKV-GEMM epilogue
#define QSCALE2 0.12752283786512624f

static __device__ __forceinline__ short f16bits(float v) {
    return __builtin_bit_cast(short, (_Float16)v);
}

template <typename T>
static __device__ __forceinline__ short8 load8_f16(const T* p) {
    if constexpr (sizeof(T) == 2) {
        return *(const short8*)p;
    } else {
        const float4 f0 = *(const float4*)p;
        const float4 f1 = *(const float4*)(p + 4);
        short8 r;
        r[0] = f16bits(f0.x); r[1] = f16bits(f0.y);
        r[2] = f16bits(f0.z); r[3] = f16bits(f0.w);
        r[4] = f16bits(f1.x); r[5] = f16bits(f1.y);
        r[6] = f16bits(f1.z); r[7] = f16bits(f1.w);
        return r;
    }
}

static __device__ __forceinline__ void storeC(float* C, size_t idx, float v) {
    C[idx] = v;
}
static __device__ __forceinline__ void storeC(_Float16* C, size_t idx, float v) {
    C[idx] = (_Float16)v;
}

// async global -> LDS, 16B/lane. LDS dest: per-lane ptr == wave base + lane*16.
static __device__ __forceinline__ void gload16(const short* g, short* l) {
    __builtin_amdgcn_global_load_lds(
        (const __attribute__((address_space(1))) void*)g,
        (__attribute__((address_space(3))) void*)l, 16, 0, 0);
}

// ---------------------------------------------------------------------------
// prep: weight transposes (+ optional fused x conversion).
// z = 0..3 : W[z] (K x N fp32) -> Wt + z*K*N ([N][K] fp16), 32x32 tile (x,y)
// z = 4..7 : convert x fp32 -> fp16, chunk = (z-4)*1024 + y*32 + x
// Launch with gridDim.z = 4 for weights-only (x may be nullptr).
// ---------------------------------------------------------------------------
__global__ __launch_bounds__(256)
void prep(const float* __restrict__ x, short* __restrict__ xb,
          const float* __restrict__ W0, const float* __restrict__ W1,
          const float* __restrict__ W2, const float* __restrict__ W3,
          short* __restrict__ Wt, int K, int N)
{
    __shared__ short T[32][33];
    const int z = blockIdx.z;
    if (z >= 4) {
        const size_t chunk = ((size_t)(z - 4) * 1024 + blockIdx.y * 32 + blockIdx.x);
        const size_t i = (chunk * 256 + threadIdx.x) * 8;
        *(short8*)&xb[i] = load8_f16(&x[i]);
        return;
    }
    const float* W = (z == 0) ? W0 : (z == 1) ? W1 : (z == 2) ? W2 : W3;
    short* Wtz = Wt + (size_t)z * K * N;

    const int n0 = blockIdx.x * 32, k0 = blockIdx.y * 32;
    const int r = threadIdx.x >> 3, c4 = (threadIdx.x & 7) * 4;

    const float4 v = *(const float4*)&W[(size_t)(k0 + r) * N + n0 + c4];
    T[r][c4 + 0] = f16bits(v.x);
    T[r][c4 + 1] = f16bits(v.y);
    T[r][c4 + 2] = f16bits(v.z);
    T[r][c4 + 3] = f16bits(v.w);
    __syncthreads();

    short4v o;
    o[0] = T[c4 + 0][r]; o[1] = T[c4 + 1][r];
    o[2] = T[c4 + 2][r]; o[3] = T[c4 + 3][r];
    *(short4v*)&Wtz[(size_t)(n0 + r) * K + k0 + c4] = o;
}

// standalone x fp32 -> fp16 chunk converter (per-batch / per-half paths)
__global__ __launch_bounds__(256)
void convx(const float* __restrict__ x, short* __restrict__ xb)
{
    const size_t i = ((size_t)blockIdx.x * 256 + threadIdx.x) * 8;
    *(short8*)&xb[i] = load8_f16(&x[i]);
}

// ---------------------------------------------------------------------------
// 128x128-tile GEMM, BK=64, global_load_lds(16B), XOR chunk-slot swizzle.
// QKV=true: N=3072; writes Q,K [b][h][s][d] and V TRANSPOSED [b][h][d][s]
//           (fused transpose_v: 4 consecutive s pack into one 8B store) at
//           slab spacing qkvStride elems; Q pre-scaled by QSCALE2.
// ---------------------------------------------------------------------------
template <typename OutT, bool QKV>
__global__ __launch_bounds__(256)
void gemm128(const short* __restrict__ A, const short* __restrict__ Bt,
             OutT* __restrict__ C, int M, int N, int K, size_t qkvStride)
{
    __shared__ __align__(16) short As[128 * 64];   // 16 KB
    __shared__ __align__(16) short Bs[128 * 64];   // 16 KB

    const int tid  = threadIdx.x;
    const int lane = tid & 63;
    const int w    = tid >> 6;
    const int quad = lane >> 4;
    const int l16  = lane & 15;

    const int m0 = blockIdx.x * 128;
    const int n0 = blockIdx.y * 128;
    const int wm = (w >> 1) * 64;
    const int wn = (w & 1) * 64;

    floatx4 acc[4][4] = {};

    const int srow   = tid >> 3;                     // 0..31
    const int schunk = (tid & 7) ^ (srow & 7);
    const short* aG = A  + (size_t)(m0 + srow) * K + schunk * 8;
    const short* bG = Bt + (size_t)(n0 + srow) * K + schunk * 8;
    short* aL = As + tid * 8;                        // round r at +r*2048
    short* bL = Bs + tid * 8;

    const int fsw = l16 & 7;                         // frag-read swizzle term

    for (int k0 = 0; k0 < K; k0 += 64) {
        __syncthreads();                             // WAR
        #pragma unroll
        for (int r = 0; r < 4; ++r) {                // row&7 invariant mod 32
            gload16(aG + k0 + (size_t)(r * 32) * K, aL + r * 2048);
            gload16(bG + k0 + (size_t)(r * 32) * K, bL + r * 2048);
        }
        __syncthreads();                             // RAW (vmcnt drained)

        #pragma unroll
        for (int kk = 0; kk < 2; ++kk) {
            short8 af[4], bf[4];
            #pragma unroll
            for (int mi = 0; mi < 4; ++mi)
                af[mi] = *(short8*)&As[(wm + mi * 16 + l16) * 64 +
                                       (((kk * 4 + quad) ^ fsw) * 8)];
            #pragma unroll
            for (int ni = 0; ni < 4; ++ni)
                bf[ni] = *(short8*)&Bs[(wn + ni * 16 + l16) * 64 +
                                       (((kk * 4 + quad) ^ fsw) * 8)];

            #pragma unroll
            for (int mi = 0; mi < 4; ++mi)
                #pragma unroll
                for (int ni = 0; ni < 4; ++ni)
                    acc[mi][ni] = MFMA_F16(af[mi], bf[ni], acc[mi][ni]);
        }
    }

    #pragma unroll
    for (int mi = 0; mi < 4; ++mi)
        #pragma unroll
        for (int ni = 0; ni < 4; ++ni) {
            if constexpr (QKV) {
                const int n   = n0 + wn + ni * 16 + l16;
                const int qkv = n >> 10, rem = n & 1023;
                const int hh  = rem >> 7, d = rem & 127;
                const int mb  = m0 + wm + mi * 16 + quad * 4;   // 4 consec rows
                const int bb  = mb >> 11, s = mb & 2047;        // s % 4 == 0
                if (qkv == 2) {
                    // V transposed [b][h][d][s]: one aligned 8B store of 4 s
                    short4v pk;
                    #pragma unroll
                    for (int r = 0; r < 4; ++r)
                        pk[r] = f16bits(acc[mi][ni][r]);
                    *(short4v*)&((short*)C)[2 * qkvStride +
                        (((size_t)bb * NHEADS + hh) * HD + d) * SEQ + s] = pk;
                } else {
                    const float sc = (qkv == 0) ? QSCALE2 : 1.0f;
                    #pragma unroll
                    for (int r = 0; r < 4; ++r)
                        storeC(C, (size_t)qkv * qkvStride +
                                  (((size_t)bb * NHEADS + hh) * SEQ + s + r) * HD + d,
                               acc[mi][ni][r] * sc);
                }
            } else {
                #pragma unroll
                for (int r = 0; r < 4; ++r) {
                    const int m = m0 + wm + mi * 16 + quad * 4 + r;
                    const int n = n0 + wn + ni * 16 + l16;
                    storeC(C, (size_t)m * N + n, acc[mi][ni][r]);
                }
            }
        }
}

// ---------------------------------------------------------------------------
// Attention v10+prio (measured 103.2-103.5us, session best): 4 waves / 64
// q-rows per block (1024 blocks = 4 indep barrier groups per CU, LDS 37KB).
// Double-buffered Ks+Vs, kt unrolled 2x, clampless v_exp_f32, l-sum via
// ones-MFMA, s_setprio(1) around QK and PV MFMA clusters (m191, +6% measured).
// ---------------------------------------------------------------------------
__global__ __launch_bounds__(256)
void attn_flash10(const short* __restrict__ Q, const short* __restrict__ K,
                  const short* __restrict__ Vt, _Float16* __restrict__ O)
{
    __shared__ __align__(16) short Ks[2][32 * 128];   // 2 x 8 KB
    __shared__ __align__(16) short Vs[2][128 * 32];   // 2 x 8 KB
    __shared__ __align__(16) short Plds[4][16 * 40];  // 5 KB  (37 KB total)

    const int tid  = threadIdx.x;
    const int lane = tid & 63;
    const int w    = tid >> 6;            // 0..3
    const int quad = lane >> 4;
    const int l16  = lane & 15;

    const int h  = blockIdx.x & 7;        // blockIdx%8 = head -> XCD L2 locality
    const int qi = blockIdx.x >> 3;       // 0..31
    const int b  = blockIdx.y;
    const int q0 = qi * 64;

    const short* Qh  = Q  + (((size_t)b * NHEADS + h) * SEQ) * HD;
    const short* Kh  = K  + (((size_t)b * NHEADS + h) * SEQ) * HD;
    const short* Vth = Vt + (((size_t)b * NHEADS + h) * HD) * SEQ;  // [d][s]

    // Q fragments (pre-scaled): A[m=l16][k = c*32 + quad*8 + j]
    const int qrow = q0 + w * 16 + l16;
    short8 qf[4];
    #pragma unroll
    for (int c = 0; c < 4; ++c)
        qf[c] = *(const short8*)&Qh[(size_t)qrow * HD + c * 32 + quad * 8];

    // staging: 256 threads cover 512 16B-slots via slots {tid, tid+256}.
    // K slot s: row = s>>4 (0..31), chunk = (s&15) ^ (row&15)
    // V slot s: row = s>>2 (0..127), chunk = (s&3) ^ ((row>>1)&3)
    const int kr0 = tid >> 4, kc0 = tid & 15;
    const int kr1 = kr0 + 16;
    const short* kGa = Kh + (size_t)kr0 * HD + ((kc0 ^ (kr0 & 15)) * 8);
    const short* kGb = Kh + (size_t)kr1 * HD + ((kc0 ^ (kr1 & 15)) * 8);
    const int vr0 = tid >> 2, vp0 = tid & 3;
    const short* vGa = Vth + (size_t)vr0 * SEQ + ((vp0 ^ ((vr0 >> 1) & 3)) * 8);
    const short* vGb = Vth + (size_t)(vr0 + 64) * SEQ + ((vp0 ^ ((vr0 >> 1) & 3)) * 8);

    floatx4 acc[8] = {};
    floatx4 acc9 = {};                    // l-sum accumulator (P @ ones)

    short8 ones;
    #pragma unroll
    for (int j = 0; j < 8; ++j) ones[j] = 0x3C00;   // fp16 1.0

    const int fswV = (l16 >> 1) & 3;      // Vs frag swizzle
    short* Pw = &Plds[w][0];

    auto STAGE = [&](short* kDst, short* vDst, int tile) {
        const size_t ko = (size_t)tile * 32 * HD;   // 32 K-rows per tile
        const size_t vo = (size_t)tile * 32;        // 32 s-cols per tile
        gload16(kGa + ko, kDst + tid * 8);
        gload16(kGb + ko, kDst + (tid + 256) * 8);
        gload16(vGa + vo, vDst + tid * 8);
        gload16(vGb + vo, vDst + (tid + 256) * 8);
    };

    auto COMPUTE = [&](const short* Kb, const short* Vb) {
        // S = Q K^T (16q x 32keys per wave)
        floatx4 s0 = {}, s1 = {};
        __builtin_amdgcn_s_setprio(1);
        #pragma unroll
        for (int c = 0; c < 4; ++c) {
            const int k_ = c * 4 + quad;
            short8 kf0 = *(short8*)&Kb[l16 * 128 + ((k_ ^ l16) * 8)];
            short8 kf1 = *(short8*)&Kb[(16 + l16) * 128 + ((k_ ^ l16) * 8)];
            s0 = MFMA_F16(qf[c], kf0, s0);
            s1 = MFMA_F16(qf[c], kf1, s1);
        }
        __builtin_amdgcn_s_setprio(0);
        // softmax (Q pre-scaled, clampless): p = 2^s; P -> wave-private LDS
        #pragma unroll
        for (int r = 0; r < 4; ++r) {
            const float p0 = __builtin_amdgcn_exp2f(s0[r]);
            const float p1 = __builtin_amdgcn_exp2f(s1[r]);
            Pw[(quad * 4 + r) * 40 + l16]      = f16bits(p0);
            Pw[(quad * 4 + r) * 40 + 16 + l16] = f16bits(p1);
        }
        short8 pf = *(short8*)&Pw[l16 * 40 + quad * 8];
        // O += P @ V (+ l-sum on the MFMA pipe)
        __builtin_amdgcn_s_setprio(1);
        acc9 = MFMA_F16(pf, ones, acc9);
        #pragma unroll
        for (int hc = 0; hc < 8; ++hc) {
            short8 vf = *(short8*)&Vb[(hc * 16 + l16) * 32 + ((quad ^ fswV) * 8)];
            acc[hc] = MFMA_F16(pf, vf, acc[hc]);
        }
        __builtin_amdgcn_s_setprio(0);
    };

    // prologue: tile 0 -> buffer 0
    STAGE(&Ks[0][0], &Vs[0][0], 0);

    for (int kt = 0; kt < SEQ; kt += 64) {
        const int t = kt >> 5;
        __syncthreads();                  // drains DMA for buf0 (tile t)
        STAGE(&Ks[1][0], &Vs[1][0], t + 1);          // t+1 <= 63 always
        COMPUTE(&Ks[0][0], &Vs[0][0]);
        __syncthreads();                  // drains DMA for buf1 (tile t+1)
        if (kt + 64 < SEQ)
            STAGE(&Ks[0][0], &Vs[0][0], t + 2);
        COMPUTE(&Ks[1][0], &Vs[1][0]);
    }

    float rinv[4];
    #pragma unroll
    for (int r = 0; r < 4; ++r)
        rinv[r] = 1.0f / fmaxf(acc9[r], 1e-30f);

    #pragma unroll
    for (int hc = 0; hc < 8; ++hc)
        #pragma unroll
        for (int r = 0; r < 4; ++r) {
            const int row = q0 + w * 16 + quad * 4 + r;
            O[((size_t)b * SEQ + row) * DMODEL + h * HD + hc * 16 + l16] =
                (_Float16)(acc[hc][r] * rinv[r]);
        }
}

// ---------------------------------------------------------------------------
// Minimal-workspace kernels (per-batch gemm64 path)
// ---------------------------------------------------------------------------
template <typename AT, typename OutT>
__global__ __launch_bounds__(256)
void gemm64(const AT* __restrict__ A, const float* __restrict__ W,
            OutT* __restrict__ C, int M, int N, int K, int headsplit)
{
    __shared__ __align__(16) short As[64][32];
    __shared__ __align__(16) short Bs[64][32];

    const int tid  = threadIdx.x;
    const int lane = tid & 63;
    const int w    = tid >> 6;
    const int quad = lane >> 4;
    const int l16  = lane & 15;

    const int m0 = blockIdx.x * 64;
    const int n0 = blockIdx.y * 64;
    const int wm = (w >> 1) * 32;
    const int wn = (w & 1) * 32;

    floatx4 acc[2][2] = {};

    const int arow = tid >> 2, acol = (tid & 3) * 8;
    const int brow = tid >> 3, bcol = (tid & 7) * 8;

    const AT*    aptr = A + (size_t)(m0 + arow) * K + acol;
    const float* bptr = W + (size_t)brow * N + n0 + bcol;

    for (int k0 = 0; k0 < K; k0 += 32) {
        short8 av = load8_f16(aptr + k0);
        short8 bv = load8_f16(bptr + (size_t)k0 * N);
        __syncthreads();
        *(short8*)&As[arow][acol] = av;
        #pragma unroll
        for (int j = 0; j < 8; ++j)
            Bs[bcol + j][brow] = bv[j];
        __syncthreads();

        short8 af0 = *(short8*)&As[wm + l16][quad * 8];
        short8 af1 = *(short8*)&As[wm + 16 + l16][quad * 8];
        short8 bf0 = *(short8*)&Bs[wn + l16][quad * 8];
        short8 bf1 = *(short8*)&Bs[wn + 16 + l16][quad * 8];

        acc[0][0] = MFMA_F16(af0, bf0, acc[0][0]);
        acc[0][1] = MFMA_F16(af0, bf1, acc[0][1]);
        acc[1][0] = MFMA_F16(af1, bf0, acc[1][0]);
        acc[1][1] = MFMA_F16(af1, bf1, acc[1][1]);
    }

    #pragma unroll
    for (int mi = 0; mi < 2; ++mi)
        #pragma unroll
        for (int ni = 0; ni < 2; ++ni)
            #pragma unroll
            for (int r = 0; r < 4; ++r) {
                const int m = m0 + wm + mi * 16 + quad * 4 + r;
                const int n = n0 + wn + ni * 16 + l16;
                const float v = acc[mi][ni][r];
                if (headsplit) {
                    const int b = m >> 11, nn = m & 2047;
                    const int h = n >> 7,  d  = n & 127;
                    storeC(C, (((size_t)b * NHEADS + h) * SEQ + nn) * HD + d, v);
                } else {
                    storeC(C, (size_t)m * N + n, v);
                }
            }
}

__global__ __launch_bounds__(256)
void attn_flash(const short* __restrict__ Q, const short* __restrict__ K,
                const short* __restrict__ V, _Float16* __restrict__ O)
{
    __shared__ __align__(16) short Ksf[32][136];
    __shared__ __align__(16) short Vtl[HD][40];
    __shared__ __align__(16) short Pldsf[4][16][40];

    const int tid  = threadIdx.x;
    const int lane = tid & 63;
    const int w    = tid >> 6;
    const int quad = lane >> 4;
    const int l16  = lane & 15;

    const int q0 = blockIdx.x * 64;
    const int h  = blockIdx.y;
    const int b  = blockIdx.z;

    const size_t headoff = ((size_t)b * NHEADS + h) * SEQ * HD;
    const short* Qh = Q + headoff;
    const short* Kh = K + headoff;
    const short* Vh = V + headoff;

    const float scale = 0.08838834764831845f;

    const int qrow = q0 + w * 16 + l16;
    short8 qf[4];
    #pragma unroll
    for (int c = 0; c < 4; ++c)
        qf[c] = *(const short8*)&Qh[(size_t)qrow * HD + c * 32 + quad * 8];

    float mrow[4], lrow[4];
    #pragma unroll
    for (int r = 0; r < 4; ++r) { mrow[r] = -1e30f; lrow[r] = 0.f; }
    floatx4 acc[8] = {};

    const int krow = tid >> 4, kcol = (tid & 15) * 8;
    const int vkey = tid & 31;
    const int vhd  = (tid >> 5) * 16;

    for (int kt = 0; kt < SEQ; kt += 32) {
        const short* Kt = Kh + (size_t)kt * HD;
        short8 k0v = *(const short8*)(Kt + (size_t)tid * 8);
        short8 k1v = *(const short8*)(Kt + (size_t)(tid + 256) * 8);
        short8 v0 = *(const short8*)&Vh[(size_t)(kt + vkey) * HD + vhd];
        short8 v1 = *(const short8*)&Vh[(size_t)(kt + vkey) * HD + vhd + 8];

        __syncthreads();
        *(short8*)&Ksf[krow][kcol]      = k0v;
        *(short8*)&Ksf[krow + 16][kcol] = k1v;
        #pragma unroll
        for (int j = 0; j < 8; ++j) {
            Vtl[vhd + j][vkey]     = v0[j];
            Vtl[vhd + 8 + j][vkey] = v1[j];
        }
        __syncthreads();

        floatx4 s0 = {}, s1 = {};
        #pragma unroll
        for (int c = 0; c < 4; ++c) {
            short8 kf0 = *(short8*)&Ksf[l16][c * 32 + quad * 8];
            short8 kf1 = *(short8*)&Ksf[16 + l16][c * 32 + quad * 8];
            s0 = MFMA_F16(qf[c], kf0, s0);
            s1 = MFMA_F16(qf[c], kf1, s1);
        }

        float p0[4], p1[4], alpha[4];
        #pragma unroll
        for (int r = 0; r < 4; ++r) {
            const float a  = s0[r] * scale;
            const float bb = s1[r] * scale;
            float mx = fmaxf(a, bb);
            mx = fmaxf(mx, __shfl_xor(mx, 1));
            mx = fmaxf(mx, __shfl_xor(mx, 2));
            mx = fmaxf(mx, __shfl_xor(mx, 4));
            mx = fmaxf(mx, __shfl_xor(mx, 8));
            const float mnew = fmaxf(mrow[r], mx);
            alpha[r] = __expf(mrow[r] - mnew);
            mrow[r]  = mnew;
            p0[r] = __expf(a - mnew);
            p1[r] = __expf(bb - mnew);
            float rs = p0[r] + p1[r];
            rs += __shfl_xor(rs, 1);
            rs += __shfl_xor(rs, 2);
            rs += __shfl_xor(rs, 4);
            rs += __shfl_xor(rs, 8);
            lrow[r] = lrow[r] * alpha[r] + rs;
        }
        #pragma unroll
        for (int hc = 0; hc < 8; ++hc)
            #pragma unroll
            for (int r = 0; r < 4; ++r)
                acc[hc][r] *= alpha[r];

        #pragma unroll
        for (int r = 0; r < 4; ++r) {
            Pldsf[w][quad * 4 + r][l16]      = f16bits(p0[r]);
            Pldsf[w][quad * 4 + r][16 + l16] = f16bits(p1[r]);
        }
        __syncthreads();

        short8 pf = *(short8*)&Pldsf[w][l16][quad * 8];
        #pragma unroll
        for (int hc = 0; hc < 8; ++hc) {
            short8 vf = *(short8*)&Vtl[hc * 16 + l16][quad * 8];
            acc[hc] = MFMA_F16(pf, vf, acc[hc]);
        }
    }

    #pragma unroll
    for (int hc = 0; hc < 8; ++hc)
        #pragma unroll
        for (int r = 0; r < 4; ++r) {
            const int row = q0 + w * 16 + quad * 4 + r;
            const float val = acc[hc][r] / fmaxf(lrow[r], 1e-30f);
            O[((size_t)b * SEQ + row) * DMODEL + h * HD + hc * 16 + l16] =
                (_Float16)val;
        }
}

extern "C" void kernel_launch(void* const* d_in, const int* in_sizes, int n_in,
                              void* d_out, int out_size, void* d_ws, size_t ws_size,
                              hipStream_t stream)
{
    const float* x  = (const float*)d_in[0];
    const float* Wq = (const float*)d_in[1];
    const float* Wk = (const float*)d_in[2];
    const float* Wv = (const float*)d_in[3];
    const float* Wo = (const float*)d_in[4];
    float* out = (float*)d_out;

    const size_t bufElems = (size_t)MROWS * DMODEL;   // 8 Mi elems (16 MiB fp16)
    const size_t batElems = (size_t)SEQ * DMODEL;     // 2 Mi elems (4 MiB fp16)
    const size_t MiB = 1024 * 1024;
    dim3 tt(256);

    if (ws_size >= 72 * MiB) {
        // layout (MiB): [0,16) xb -> later Ab | [16,32) Qb | [32,48) Kb |
        // [48,64) Vt (written transposed by QKV GEMM) | [64,72) Wt
        short* xb    = (short*)d_ws;
        short* Qb    = xb + bufElems;
        short* Kb    = xb + 2 * bufElems;
        short* Vtb   = xb + 3 * bufElems;      // V transposed [b][h][d][s]
        short* Wtall = xb + 4 * bufElems;      // Wq^T,Wk^T,Wv^T,Wo^T contiguous
        short* Wto   = Wtall + 3 * (size_t)DMODEL * DMODEL;
        short* Ab    = xb;                     // alias: xb dead after QKV GEMM

        prep<<<dim3(32, 32, 8), tt, 0, stream>>>(
            x, xb, Wq, Wk, Wv, Wo, Wtall, DMODEL, DMODEL);

        gemm128<_Float16, true><<<dim3(MROWS / 128, NQKV / 128), tt, 0, stream>>>(
            xb, Wtall, (_Float16*)Qb, MROWS, NQKV, DMODEL, bufElems);

        attn_flash10<<<dim3(NHEADS * (SEQ / 64), BATCH), tt, 0, stream>>>(
            Qb, Kb, Vtb, (_Float16*)Ab);

        gemm128<float, false><<<dim3(MROWS / 128, DMODEL / 128), tt, 0, stream>>>(
            Ab, Wto, out, MROWS, DMODEL, DMODEL, 0);
    } else if (ws_size >= 64 * MiB) {
        // half-split: [0,8) xb (half of x) -> later Ab (per half) | [8,24) Qb |
        // [24,40) Kb | [40,56) Vt (transposed by GEMM) | [56,64) Wt
        short* xb    = (short*)d_ws;                  // 4 Mi elems
        short* Qb    = xb + 2 * batElems;             // 8 Mi elems
        short* Kb    = Qb + 4 * batElems;
        short* Vtb   = Kb + 4 * batElems;
        short* Wtall = Vtb + 4 * batElems;
        short* Wto   = Wtall + 3 * (size_t)DMODEL * DMODEL;

        prep<<<dim3(32, 32, 4), tt, 0, stream>>>(     // weights only
            nullptr, nullptr, Wq, Wk, Wv, Wo, Wtall, DMODEL, DMODEL);

        for (int half = 0; half < 2; ++half) {
            const size_t off = (size_t)half * 2 * batElems;   // 2 batches
            convx<<<dim3(2048), tt, 0, stream>>>(x + off, xb);
            gemm128<_Float16, true><<<dim3(32, NQKV / 128), tt, 0, stream>>>(
                xb, Wtall, (_Float16*)(Qb + off), 2 * SEQ, NQKV, DMODEL,
                4 * batElems);                         // Q->K->Vt slab spacing
        }
        for (int half = 0; half < 2; ++half) {
            const size_t off = (size_t)half * 2 * batElems;
            attn_flash10<<<dim3(NHEADS * (SEQ / 64), 2), tt, 0, stream>>>(
                Qb + off, Kb + off, Vtb + off, (_Float16*)xb);   // Ab = xb
            gemm128<float, false><<<dim3(32, DMODEL / 128), tt, 0, stream>>>(
                xb, Wto, out + off, 2 * SEQ, DMODEL, DMODEL, 0);
        }
    } else if (ws_size >= 24 * MiB) {
        // per-batch: [0,4) xb -> Ab | [4,8) Qb | [8,12) Kb | [12,16) Vt |
        // [16,24) Wt.  4 launches per batch, sequential on stream.
        short* xb    = (short*)d_ws;
        short* Qb    = xb + batElems;
        short* Kb    = xb + 2 * batElems;
        short* Vtb   = xb + 3 * batElems;
        short* Wtall = xb + 4 * batElems;
        short* Wto   = Wtall + 3 * (size_t)DMODEL * DMODEL;

        prep<<<dim3(32, 32, 4), tt, 0, stream>>>(     // weights only
            nullptr, nullptr, Wq, Wk, Wv, Wo, Wtall, DMODEL, DMODEL);

        for (int b = 0; b < BATCH; ++b) {
            convx<<<dim3(1024), tt, 0, stream>>>(x + (size_t)b * batElems, xb);
            gemm128<_Float16, true><<<dim3(SEQ / 128, NQKV / 128), tt, 0, stream>>>(
                xb, Wtall, (_Float16*)Qb, SEQ, NQKV, DMODEL, batElems);
            attn_flash10<<<dim3(NHEADS * (SEQ / 64), 1), tt, 0, stream>>>(
                Qb, Kb, Vtb, (_Float16*)xb);          // Ab = xb
            gemm128<float, false><<<dim3(SEQ / 128, DMODEL / 128), tt, 0, stream>>>(
                xb, Wto, out + (size_t)b * batElems, SEQ, DMODEL, DMODEL, 0);
        }
    } else {
        // last resort (>=16 MiB): per-batch gemm64 path, weights read fp32.
        short* Qb = (short*)d_ws;
        short* Kb = Qb + batElems;
        short* Vb = Qb + 2 * batElems;
        short* Ab = Qb + 3 * batElems;

        dim3 gg(SEQ / 64, DMODEL / 64);
        for (int b = 0; b < BATCH; ++b) {
            const float* xb_ = x + (size_t)b * batElems;
            gemm64<float, _Float16><<<gg, tt, 0, stream>>>(
                xb_, Wq, (_Float16*)Qb, SEQ, DMODEL, DMODEL, 1);
            gemm64<float, _Float16><<<gg, tt, 0, stream>>>(
                xb_, Wk, (_Float16*)Kb, SEQ, DMODEL, DMODEL, 1);
            gemm64<float, _Float16><<<gg, tt, 0, stream>>>(
                xb_, Wv, (_Float16*)Vb, SEQ, DMODEL, DMODEL, 1);
            attn_flash<<<dim3(SEQ / 64, NHEADS, 1), tt, 0, stream>>>(
                Qb, Kb, Vb, (_Float16*)Ab);
            gemm64<short, float><<<gg, tt, 0, stream>>>(
                Ab, Wo, out + (size_t)b * batElems, SEQ, DMODEL, DMODEL, 0);
        }
    }
}